// Round 1
// baseline (18340.988 us; speedup 1.0000x reference)
//
#include <hip/hip_runtime.h>

// HierarchicalLstmDecoder on MI355X (gfx950).
// B=128, S=16, L=16, T=256, Z=512, HC=1024, E=512, HD=1024, V=1024.
// Strategy: bf16 MFMA (16x16x32) for all GEMMs, fp32 accumulate + fp32 gate math.
// Sequential LSTM recurrence as per-step kernels; input projections as big GEMMs.

typedef float  floatx4 __attribute__((ext_vector_type(4)));
typedef __bf16 bf16x8  __attribute__((ext_vector_type(8)));
typedef unsigned short u16;

#define MFMA16(a, b, c) __builtin_amdgcn_mfma_f32_16x16x32_bf16(a, b, c, 0, 0, 0)

__device__ __forceinline__ u16 f2b(float f) {
  unsigned int u = __float_as_uint(f);
  u += 0x7fffu + ((u >> 16) & 1u);            // RNE
  return (u16)(u >> 16);
}
__device__ __forceinline__ float sigf(float x) { return 1.f / (1.f + __expf(-x)); }
__device__ __forceinline__ float tanhf_fast(float x) {
  float e = __expf(-2.f * fabsf(x));
  float r = (1.f - e) / (1.f + e);
  return x >= 0.f ? r : -r;
}

// ---------------- casts ----------------
__global__ void cast_f2b(const float* __restrict__ s, u16* __restrict__ d, int n4) {
  int i = blockIdx.x * blockDim.x + threadIdx.x;
  if (i < n4) {
    float4 v = ((const float4*)s)[i];
    u16* o = d + (size_t)i * 4;
    o[0] = f2b(v.x); o[1] = f2b(v.y); o[2] = f2b(v.z); o[3] = f2b(v.w);
  }
}

// dst[r*2^clog2 + c] = bf16(src[r*sstride + soff + c]); grid covers rows<<clog2 exactly.
__global__ void cast_slice(const float* __restrict__ s, u16* __restrict__ d,
                           int sstride, int soff, int clog2) {
  int idx = blockIdx.x * blockDim.x + threadIdx.x;
  int r = idx >> clog2;
  int c = idx & ((1 << clog2) - 1);
  d[idx] = f2b(s[(size_t)r * sstride + soff + c]);
}

// ---------------- generic GEMM:  C[M,N] = act(A @ W^T + b1 + b2) ----------------
// A: bf16, row r mapped per AMODE; W: bf16 [N,K] (PyTorch Linear layout).
// AMODE 0: arow = r (A row stride = K).
// AMODE 1: r=(b,tt) with b=r>>6, tt=r&63; t=t0+tt; arow=b*256+t-SHIFT (zeros when SHIFT && t==0).
// Outputs: Cf fp32 and/or Cb bf16 (nullable), row-major [M,N].
template <int AMODE, int SHIFT, int ACT>
__global__ __launch_bounds__(256) void gemm_kernel(
    const u16* __restrict__ A, const u16* __restrict__ W,
    const float* __restrict__ b1, const float* __restrict__ b2,
    float* __restrict__ Cf, u16* __restrict__ Cb,
    int M, int N, int K, int t0) {
  int tid = threadIdx.x;
  int lane = tid & 63, wave = tid >> 6;
  int lr = lane & 15, lk = (lane >> 4) * 8;
  int mblk = blockIdx.y * 128 + (wave >> 1) * 64;
  int nblk = blockIdx.x * 128 + (wave & 1) * 64;

  bf16x8 zf;
#pragma unroll
  for (int q = 0; q < 8; ++q) zf[q] = (__bf16)0.f;

  const u16* ap[4];
  bool aval[4];
#pragma unroll
  for (int i = 0; i < 4; ++i) {
    int r = mblk + i * 16 + lr;
    long arow;
    bool v = true;
    if (AMODE == 0) {
      arow = r;
    } else {
      int b = r >> 6, tt = r & 63;
      int t = t0 + tt;
      arow = (long)b * 256 + t - SHIFT;
      if (SHIFT && t == 0) { v = false; arow = 0; }
    }
    ap[i] = A + (size_t)arow * K + lk;
    aval[i] = v;
  }
  const u16* wp[4];
#pragma unroll
  for (int j = 0; j < 4; ++j) wp[j] = W + (size_t)(nblk + j * 16 + lr) * K + lk;

  floatx4 zero4 = {0.f, 0.f, 0.f, 0.f};
  floatx4 acc[4][4];
#pragma unroll
  for (int i = 0; i < 4; ++i)
#pragma unroll
    for (int j = 0; j < 4; ++j) acc[i][j] = zero4;

  for (int k = 0; k < K; k += 32) {
    bf16x8 av[4], bv[4];
#pragma unroll
    for (int i = 0; i < 4; ++i) {
      bf16x8 t = *(const bf16x8*)(ap[i] + k);
      if (AMODE == 1 && SHIFT) { if (!aval[i]) t = zf; }
      av[i] = t;
    }
#pragma unroll
    for (int j = 0; j < 4; ++j) bv[j] = *(const bf16x8*)(wp[j] + k);
#pragma unroll
    for (int i = 0; i < 4; ++i)
#pragma unroll
      for (int j = 0; j < 4; ++j) acc[i][j] = MFMA16(av[i], bv[j], acc[i][j]);
  }

  // C/D layout: col = lane&15, row = (lane>>4)*4 + reg
#pragma unroll
  for (int i = 0; i < 4; ++i) {
    int rowb = mblk + i * 16 + (lane >> 4) * 4;
#pragma unroll
    for (int j = 0; j < 4; ++j) {
      int col = nblk + j * 16 + lr;
      float bias = 0.f;
      if (b1) bias += b1[col];
      if (b2) bias += b2[col];
#pragma unroll
      for (int r = 0; r < 4; ++r) {
        float v = acc[i][j][r] + bias;
        if (ACT == 1) v = tanhf_fast(v);
        size_t off = (size_t)(rowb + r) * N + col;
        if (Cf) Cf[off] = v;
        if (Cb) Cb[off] = f2b(v);
      }
    }
  }
}

// ---------------- LSTM recurrence step ----------------
// Gates G[b, 4096] = gx[b,:] (+ eadd[b,:]) + h_prev[b,:] @ Whh^T; then
// c = sig(f)*c + sig(i)*tanh(g); h = sig(o)*tanh(c).
// Grid 128 WGs: wg&1 -> 64-row batch half, wg>>1 -> 16-wide j slice.
// Wave w computes gate w's 64x16 tile (K=1024); gate exchange via LDS.
__global__ __launch_bounds__(256) void lstm_step(
    const float* __restrict__ gx, int gx_bstride, int gx_off,
    const float* __restrict__ eadd, int e_bstride, int e_off,
    const u16* __restrict__ hp, int hp_bstride,   // pre-offset to step t-1; null if t==0
    const u16* __restrict__ Whh,                  // [4096, 1024] bf16
    float* __restrict__ c, int czero,
    u16* __restrict__ hout, int ho_bstride)       // pre-offset to step t
{
  __shared__ float G[4][64][17];
  int tid = threadIdx.x;
  int lane = tid & 63, wave = tid >> 6;
  int lr = lane & 15, lk = (lane >> 4) * 8;
  int wg = blockIdx.x;
  int mbase = (wg & 1) * 64;
  int j0 = (wg >> 1) * 16;
  int n0 = wave * 1024 + j0;

  floatx4 zero4 = {0.f, 0.f, 0.f, 0.f};
  floatx4 acc[4];
#pragma unroll
  for (int i = 0; i < 4; ++i) acc[i] = zero4;

  if (hp) {
    const u16* hpp[4];
#pragma unroll
    for (int i = 0; i < 4; ++i)
      hpp[i] = hp + (size_t)(mbase + i * 16 + lr) * hp_bstride + lk;
    const u16* wpp = Whh + (size_t)(n0 + lr) * 1024 + lk;
#pragma unroll 4
    for (int k = 0; k < 1024; k += 32) {
      bf16x8 bv = *(const bf16x8*)(wpp + k);
#pragma unroll
      for (int i = 0; i < 4; ++i) {
        bf16x8 av = *(const bf16x8*)(hpp[i] + k);
        acc[i] = MFMA16(av, bv, acc[i]);
      }
    }
  }

#pragma unroll
  for (int i = 0; i < 4; ++i) {
    int mloc = i * 16 + (lane >> 4) * 4;
    int col = n0 + lr;
#pragma unroll
    for (int r = 0; r < 4; ++r) {
      int b = mbase + mloc + r;
      float v = acc[i][r] + gx[(size_t)b * gx_bstride + gx_off + col];
      if (eadd) v += eadd[(size_t)b * e_bstride + e_off + col];
      G[wave][mloc + r][lr] = v;
    }
  }
  __syncthreads();

  for (int e = tid; e < 1024; e += 256) {
    int m = e >> 4, j = e & 15;
    int b = mbase + m, jj = j0 + j;
    float iv = G[0][m][j], fv = G[1][m][j], gv = G[2][m][j], ov = G[3][m][j];
    float cp = czero ? 0.f : c[(size_t)b * 1024 + jj];
    float cn = sigf(fv) * cp + sigf(iv) * tanhf_fast(gv);
    float h = sigf(ov) * tanhf_fast(cn);
    c[(size_t)b * 1024 + jj] = cn;
    hout[(size_t)b * ho_bstride + jj] = f2b(h);
  }
}

// ---------------- host ----------------
extern "C" void kernel_launch(void* const* d_in, const int* in_sizes, int n_in,
                              void* d_out, int out_size, void* d_ws, size_t ws_size,
                              hipStream_t stream) {
  const float* z      = (const float*)d_in[0];
  const float* x      = (const float*)d_in[1];
  const float* fcz_w  = (const float*)d_in[2];
  const float* fcz_b  = (const float*)d_in[3];
  const float* c_wih  = (const float*)d_in[4];
  const float* c_whh  = (const float*)d_in[5];
  const float* c_bih  = (const float*)d_in[6];
  const float* c_bhh  = (const float*)d_in[7];
  const float* fcc_w  = (const float*)d_in[8];
  const float* fcc_b  = (const float*)d_in[9];
  const float* d0_wih = (const float*)d_in[10];
  const float* d0_whh = (const float*)d_in[11];
  const float* d0_bih = (const float*)d_in[12];
  const float* d0_bhh = (const float*)d_in[13];
  const float* d1_wih = (const float*)d_in[14];
  const float* d1_whh = (const float*)d_in[15];
  const float* d1_bih = (const float*)d_in[16];
  const float* d1_bhh = (const float*)d_in[17];
  const float* out_w  = (const float*)d_in[18];
  const float* out_b  = (const float*)d_in[19];
  float* out = (float*)d_out;
  (void)in_sizes; (void)n_in; (void)out_size; (void)ws_size;

  char* ws = (char*)d_ws;
  size_t cur = 0;
  auto alloc = [&](size_t elems, size_t esz) -> void* {
    void* p = ws + cur;
    cur += (elems * esz + 255) & ~(size_t)255;
    return p;
  };
  u16*   wz      = (u16*)alloc(1024 * 512, 2);
  u16*   wcih    = (u16*)alloc(4096 * 1024, 2);
  u16*   wchh    = (u16*)alloc(4096 * 1024, 2);
  u16*   wfcc    = (u16*)alloc(512 * 1024, 2);
  u16*   w0v     = (u16*)alloc(4096 * 1024, 2);
  u16*   w0e     = (u16*)alloc(4096 * 512, 2);
  u16*   w0hh    = (u16*)alloc(4096 * 1024, 2);
  u16*   w1ih    = (u16*)alloc(4096 * 1024, 2);
  u16*   w1hh    = (u16*)alloc(4096 * 1024, 2);
  u16*   woutw   = (u16*)alloc(1024 * 1024, 2);
  u16*   zb      = (u16*)alloc(2048 * 512, 2);
  u16*   xb      = (u16*)alloc((size_t)32768 * 1024, 2);
  u16*   condinb = (u16*)alloc(2048 * 1024, 2);
  float* gxs     = (float*)alloc((size_t)2048 * 4096, 4);  // shared: gxc then embgx
  u16*   condh   = (u16*)alloc(2048 * 1024, 2);
  float* cc      = (float*)alloc(128 * 1024, 4);
  u16*   embb    = (u16*)alloc(2048 * 512, 2);
  float* gxbuf   = (float*)alloc((size_t)8192 * 4096, 4);  // chunk gate buffer (64 steps)
  u16*   h0b     = (u16*)alloc((size_t)32768 * 1024, 2);
  float* c0      = (float*)alloc(128 * 1024, 4);
  u16*   h1b     = (u16*)alloc((size_t)32768 * 1024, 2);
  float* c1      = (float*)alloc(128 * 1024, 4);

  auto cast = [&](const float* s, u16* d, size_t n) {
    cast_f2b<<<dim3((unsigned)(n / 1024)), dim3(256), 0, stream>>>(s, d, (int)(n / 4));
  };
  cast(fcz_w, wz, (size_t)1024 * 512);
  cast(c_wih, wcih, (size_t)4096 * 1024);
  cast(c_whh, wchh, (size_t)4096 * 1024);
  cast(fcc_w, wfcc, (size_t)512 * 1024);
  cast(d0_whh, w0hh, (size_t)4096 * 1024);
  cast(d1_wih, w1ih, (size_t)4096 * 1024);
  cast(d1_whh, w1hh, (size_t)4096 * 1024);
  cast(out_w, woutw, (size_t)1024 * 1024);
  cast(z, zb, (size_t)2048 * 512);
  cast(x, xb, (size_t)32768 * 1024);
  cast_slice<<<dim3(4096 * 1024 / 256), dim3(256), 0, stream>>>(d0_wih, w0v, 1536, 0, 10);
  cast_slice<<<dim3(4096 * 512 / 256), dim3(256), 0, stream>>>(d0_wih, w0e, 1536, 1024, 9);

  // conductor input: condinb[b*16+s, :] = bf16(z @ fcz_w^T + fcz_b)
  gemm_kernel<0, 0, 0><<<dim3(1024 / 128, 2048 / 128), dim3(256), 0, stream>>>(
      zb, wz, fcz_b, nullptr, nullptr, condinb, 2048, 1024, 512, 0);
  // conductor gates input proj: gxs = condin @ c_wih^T + c_bih + c_bhh
  gemm_kernel<0, 0, 0><<<dim3(4096 / 128, 2048 / 128), dim3(256), 0, stream>>>(
      condinb, wcih, c_bih, c_bhh, gxs, nullptr, 2048, 4096, 1024, 0);
  // conductor recurrence (16 steps) -> condh bf16 [B,S,HC]
  for (int s = 0; s < 16; ++s) {
    const u16* hp = (s == 0) ? nullptr : condh + (size_t)(s - 1) * 1024;
    lstm_step<<<dim3(128), dim3(256), 0, stream>>>(
        gxs, 16 * 4096, s * 4096,
        nullptr, 0, 0,
        hp, 16 * 1024,
        wchh, cc, (s == 0) ? 1 : 0,
        condh + (size_t)s * 1024, 16 * 1024);
  }
  // emb = tanh(condh @ fcc_w^T + fcc_b), bf16
  gemm_kernel<0, 0, 1><<<dim3(512 / 128, 2048 / 128), dim3(256), 0, stream>>>(
      condh, wfcc, fcc_b, nullptr, nullptr, embb, 2048, 512, 1024, 0);
  // embgx = emb @ d0_wih[:, V:]^T  (no bias; biases carried in gx0)
  gemm_kernel<0, 0, 0><<<dim3(4096 / 128, 2048 / 128), dim3(256), 0, stream>>>(
      embb, w0e, nullptr, nullptr, gxs, nullptr, 2048, 4096, 512, 0);

  // decoder layer 0: per 64-step chunk, gx0 = prev_token @ W0v^T + b_ih + b_hh, then steps
  for (int ch = 0; ch < 4; ++ch) {
    gemm_kernel<1, 1, 0><<<dim3(4096 / 128, 8192 / 128), dim3(256), 0, stream>>>(
        xb, w0v, d0_bih, d0_bhh, gxbuf, nullptr, 8192, 4096, 1024, ch * 64);
    for (int tt = 0; tt < 64; ++tt) {
      int t = ch * 64 + tt;
      const u16* hp = (t == 0) ? nullptr : h0b + (size_t)(t - 1) * 1024;
      lstm_step<<<dim3(128), dim3(256), 0, stream>>>(
          gxbuf, 64 * 4096, tt * 4096,
          gxs, 16 * 4096, (t >> 4) * 4096,
          hp, 256 * 1024,
          w0hh, c0, (t == 0) ? 1 : 0,
          h0b + (size_t)t * 1024, 256 * 1024);
    }
  }
  // decoder layer 1: gx1 = h0 @ d1_wih^T + b, then steps
  for (int ch = 0; ch < 4; ++ch) {
    gemm_kernel<1, 0, 0><<<dim3(4096 / 128, 8192 / 128), dim3(256), 0, stream>>>(
        h0b, w1ih, d1_bih, d1_bhh, gxbuf, nullptr, 8192, 4096, 1024, ch * 64);
    for (int tt = 0; tt < 64; ++tt) {
      int t = ch * 64 + tt;
      const u16* hp = (t == 0) ? nullptr : h1b + (size_t)(t - 1) * 1024;
      lstm_step<<<dim3(128), dim3(256), 0, stream>>>(
          gxbuf, 64 * 4096, tt * 4096,
          nullptr, 0, 0,
          hp, 256 * 1024,
          w1hh, c1, (t == 0) ? 1 : 0,
          h1b + (size_t)t * 1024, 256 * 1024);
    }
  }
  // logits = h1 @ out_w^T + out_b -> d_out [B,T,V]
  gemm_kernel<0, 0, 0><<<dim3(1024 / 128, 32768 / 128), dim3(256), 0, stream>>>(
      h1b, woutw, out_b, nullptr, out, nullptr, 32768, 1024, 1024, 0);
}